// Round 2
// baseline (288.419 us; speedup 1.0000x reference)
//
#include <hip/hip_runtime.h>
#include <stdint.h>

// QuantumDeepField — MI355X (gfx950)
// Pipeline:
//   k_prep   : c_n (per-(b,d) norm over A), z/q unpack, u/w fold of layer-1,
//              W2/W3 -> bf16 swizzled ws, out[b] = W_prop_b, zero M
//   k_corr   : systematic bf16-error correction at dens=0, adds G*corr to out
//   k_M      : M[b] = gto^T gto via MFMA (bf16 inputs, f32 acc)
//   k_cct    : S_mo = e^T M e ; cct[b][d][a] = c_n*inv_na*alpha (bf16 swizzled)
//   k_main   : 1024-thr blocks, 256-row grid tiles: gto -> mo (MFMA) ->
//              density -> v1 -> L2 (MFMA) -> L3 (MFMA) -> sum -> out[b]

#define BB 8
#define GG 32768
#define AA 64
#define DD 128
#define EPSF 1e-12f

// ---- workspace layout (byte offsets) ----
#define WS_M    0u          // [B][64][64] f32 Gram (131072 B)
#define WS_ZQ   131072u     // [B][64][2] f32 {zeta, q-1} (4096 B)
#define WS_CN   135168u     // [B][64][128] f32 c_n (262144 B)
#define WS_UW   397312u     // u[128], w[128] f32 (1024 B)
#define WS_CCT  398336u     // [B][128][64] bf16 swizzled (131072 B)
#define WS_W2   529408u     // [128][128] bf16 swizzled (32768 B)
#define WS_W3   562176u     // [128][128] bf16 swizzled (32768 B) -> end 594944

typedef __attribute__((ext_vector_type(8))) short bf16x8;
typedef __attribute__((ext_vector_type(4))) float f32x4;

__device__ __forceinline__ unsigned short f2bf(float f) {
    union { float f; unsigned int u; } x; x.f = f;
    unsigned int u = x.u + 0x7FFFu + ((x.u >> 16) & 1u);
    return (unsigned short)(u >> 16);
}
__device__ __forceinline__ float bfround(float f) {
    union { float f; unsigned int u; } x; x.f = f;
    unsigned int u = x.u + 0x7FFFu + ((x.u >> 16) & 1u);
    x.u = u & 0xFFFF0000u;
    return x.f;
}

// ---------------- k_prep ----------------
__global__ __launch_bounds__(256)
void k_prep(const int* __restrict__ q, const int* __restrict__ ao,
            const float* __restrict__ coef, const float* __restrict__ zeta,
            const float* __restrict__ wpre_w, const float* __restrict__ wpre_b,
            const float* __restrict__ wfunc_w, const float* __restrict__ wfunc_b,
            const float* __restrict__ wprop_b, float* __restrict__ out,
            char* __restrict__ ws)
{
    int tid = blockIdx.x * 256 + threadIdx.x;
    if (tid < 32768) {
        // W2/W3 -> bf16, row-swizzled (byte ^= (row&7)<<4), row = output e
        int lsel = tid >> 14;           // 0 -> layer 2, 1 -> layer 3
        int idx = tid & 16383;
        int e = idx >> 7, dd = idx & 127;
        float v = wfunc_w[(lsel + 1) * 16384 + idx];
        unsigned short* dst = (unsigned short*)(ws + (lsel == 0 ? WS_W2 : WS_W3));
        int off = e * 256 + ((dd * 2) ^ ((e & 7) << 4));
        dst[off >> 1] = f2bf(v);
    } else if (tid < 33792) {
        // c_n: per-(b,d) L2 norm over A
        int i = tid - 32768;
        int b = i >> 7, dd = i & 127;
        float s = 0.f;
        for (int a = 0; a < AA; ++a) {
            float v = coef[ao[b * AA + a] * DD + dd];
            s += v * v;
        }
        float inv = 1.f / fmaxf(sqrtf(s), EPSF);
        float* cn = (float*)(ws + WS_CN);
        for (int a = 0; a < AA; ++a)
            cn[((size_t)b * AA + a) * DD + dd] = coef[ao[b * AA + a] * DD + dd] * inv;
    } else if (tid < 34304) {
        int i = tid - 33792;
        int b = i >> 6, a = i & 63;
        float* zq = (float*)(ws + WS_ZQ);
        zq[(b * AA + a) * 2 + 0] = zeta[ao[b * AA + a]];
        zq[(b * AA + a) * 2 + 1] = (float)q[b * AA + a];   // q-1 in {0,1,2}
    } else if (tid < 34432) {
        // fold layer-1: u = W1 @ w_pre ; w = W1 @ b_pre + b1
        int e = tid - 34304;
        float su = 0.f, sw = 0.f;
        for (int dd = 0; dd < DD; ++dd) {
            float wv = wfunc_w[e * DD + dd];
            su += wv * wpre_w[dd];
            sw += wv * wpre_b[dd];
        }
        float* uw = (float*)(ws + WS_UW);
        uw[e] = su;
        uw[128 + e] = sw + wfunc_b[e];
    } else if (tid < 34440) {
        out[tid - 34432] = wprop_b[0];
    } else if (tid < 67208) {
        ((float*)(ws + WS_M))[tid - 34440] = 0.f;
    }
}

// ---------------- k_corr : cancel systematic bf16 error ----------------
__global__ __launch_bounds__(128)
void k_corr(const float* __restrict__ wfunc_w, const float* __restrict__ wfunc_b,
            const float* __restrict__ wprop_w, float* __restrict__ out,
            char* __restrict__ ws)
{
    __shared__ float v1e[128], v1b[128], v2e[128], v2b[128];
    __shared__ float part[2];
    int t = threadIdx.x;
    const float* uw = (const float*)(ws + WS_UW);
    float w0 = uw[128 + t];
    float r = fmaxf(w0, 0.f);
    v1e[t] = r;
    v1b[t] = bfround(r);
    __syncthreads();
    float ze = wfunc_b[128 + t], zb = ze;
    for (int dd = 0; dd < 128; ++dd) {
        float wv = wfunc_w[16384 + t * 128 + dd];
        ze += wv * v1e[dd];
        zb += bfround(wv) * v1b[dd];
    }
    v2e[t] = fmaxf(ze, 0.f);
    v2b[t] = bfround(fmaxf(zb, 0.f));
    __syncthreads();
    float ye = wfunc_b[256 + t], yb = ye;
    for (int dd = 0; dd < 128; ++dd) {
        float wv = wfunc_w[32768 + t * 128 + dd];
        ye += wv * v2e[dd];
        yb += bfround(wv) * v2b[dd];
    }
    float wpv = wprop_w[t];
    float diff = (fmaxf(ye, 0.f) - fmaxf(yb, 0.f)) * wpv;
    #pragma unroll
    for (int m = 1; m < 64; m <<= 1) diff += __shfl_xor(diff, m);
    if ((t & 63) == 0) part[t >> 6] = diff;
    __syncthreads();
    if (t == 0) {
        float corr = (part[0] + part[1]) * (float)GG;
        #pragma unroll
        for (int b = 0; b < BB; ++b) atomicAdd(&out[b], corr);
    }
}

// ---------------- k_M : Gram matrix via MFMA ----------------
// grid (32, B), 1024 threads. Each block: 1024 g's = 8 tiles of 128.
// LDS: gto transposed [64 a][128 g] bf16, row stride 256B, XOR-swizzled.
__global__ __launch_bounds__(1024, 4)
void k_M(const float* __restrict__ dmat, char* __restrict__ ws)
{
    __shared__ unsigned short gs[8192];   // 16 KB
    const int b = blockIdx.y;
    const int chunk = blockIdx.x;
    const int t = threadIdx.x;
    const int srow = t >> 3;              // g within tile (0..127)
    const int ao8 = t & 7;                // a-chunk: a = ao8*8 + j

    // per-thread zeta/q for its 8 fixed a's
    const float* zqp = (const float*)(ws + WS_ZQ) + b * 128;
    float zz[8], qm[8];
    #pragma unroll
    for (int j = 0; j < 8; ++j) {
        zz[j] = zqp[(ao8 * 8 + j) * 2];
        qm[j] = zqp[(ao8 * 8 + j) * 2 + 1];
    }

    const int wv = t >> 6, l = t & 63;
    const int ta = wv >> 2, tb = wv & 3;
    const int lrow = l & 15, lk = l >> 4;

    const float* dbase = dmat + (size_t)b * GG * AA + (size_t)chunk * 1024 * AA;

    f32x4 acc = (f32x4){0.f, 0.f, 0.f, 0.f};

    float4 pf0, pf1;
    {
        const float4* p = (const float4*)(dbase + (size_t)srow * AA + ao8 * 8);
        pf0 = p[0]; pf1 = p[1];
    }

    for (int tt = 0; tt < 8; ++tt) {
        // gto -> LDS transposed
        float dv[8] = {pf0.x, pf0.y, pf0.z, pf0.w, pf1.x, pf1.y, pf1.z, pf1.w};
        #pragma unroll
        for (int j = 0; j < 8; ++j) {
            int a = ao8 * 8 + j;
            float ttv = zz[j] * dv[j];
            float ex = __expf(-ttv * ttv);
            float pw = (qm[j] < 0.5f) ? 1.f : ((qm[j] < 1.5f) ? dv[j] : dv[j] * dv[j]);
            int off = a * 256 + ((srow * 2) ^ ((a & 7) << 4));
            gs[off >> 1] = f2bf(pw * ex);
        }
        // prefetch next tile
        if (tt < 7) {
            const float4* p = (const float4*)(dbase + (size_t)((tt + 1) * 128 + srow) * AA + ao8 * 8);
            pf0 = p[0]; pf1 = p[1];
        }
        __syncthreads();
        // Gram MFMA: wave (ta,tb) tile, K=128 in 4 slices
        #pragma unroll
        for (int kt = 0; kt < 4; ++kt) {
            int colB = kt * 64 + lk * 16;
            int ra = ta * 16 + lrow;
            int rb = tb * 16 + lrow;
            bf16x8 af = *(const bf16x8*)((const char*)gs + ra * 256 + (colB ^ ((ra & 7) << 4)));
            bf16x8 bf = *(const bf16x8*)((const char*)gs + rb * 256 + (colB ^ ((rb & 7) << 4)));
            acc = __builtin_amdgcn_mfma_f32_16x16x32_bf16(af, bf, acc, 0, 0, 0);
        }
        __syncthreads();
    }

    float* Mg = (float*)(ws + WS_M) + b * 4096;
    #pragma unroll
    for (int r = 0; r < 4; ++r)
        atomicAdd(&Mg[(ta * 16 + lk * 4 + r) * 64 + tb * 16 + lrow], acc[r]);
}

// ---------------- k_cct : S_mo = e^T M e ; folded coeffs ----------------
__global__ __launch_bounds__(256)
void k_cct(const float* __restrict__ Ne, char* __restrict__ ws)
{
    __shared__ float M[64][64];
    __shared__ float e_s[128][65];
    __shared__ float inv_na[64];
    __shared__ float alpha[128];
    const int b = blockIdx.x, t = threadIdx.x;
    const float* Mg = (const float*)(ws + WS_M) + b * 4096;
    for (int i = t; i < 4096; i += 256) ((float*)M)[i] = Mg[i];
    __syncthreads();
    if (t < 64) inv_na[t] = 1.f / fmaxf(sqrtf(M[t][t]), EPSF);
    __syncthreads();
    const float* cn = (const float*)(ws + WS_CN) + (size_t)b * AA * DD;
    for (int i = t; i < 8192; i += 256) {
        int a = i >> 7, dd = i & 127;
        e_s[dd][a] = cn[a * DD + dd] * inv_na[a];
    }
    __syncthreads();
    const int d = t >> 1, half = t & 1;
    float y[32];
    #pragma unroll
    for (int j = 0; j < 32; ++j) y[j] = 0.f;
    for (int a = 0; a < 64; ++a) {
        float ea = e_s[d][a];
        const float4* Mr = (const float4*)&M[a][half * 32];
        #pragma unroll 8
        for (int j4 = 0; j4 < 8; ++j4) {
            float4 mv = Mr[j4];
            y[4 * j4 + 0] += ea * mv.x; y[4 * j4 + 1] += ea * mv.y;
            y[4 * j4 + 2] += ea * mv.z; y[4 * j4 + 3] += ea * mv.w;
        }
    }
    float s = 0.f;
    #pragma unroll 8
    for (int j = 0; j < 32; ++j) s += e_s[d][half * 32 + j] * y[j];
    s += __shfl_xor(s, 1);
    if (half == 0) alpha[d] = sqrtf(Ne[b] * (1.f / 128.f)) / fmaxf(sqrtf(s), EPSF);
    __syncthreads();
    unsigned short* cct = (unsigned short*)(ws + WS_CCT) + (size_t)b * 8192;
    for (int i = t; i < 8192; i += 256) {
        int dd = i >> 6, a = i & 63;
        float v = e_s[dd][a] * alpha[dd];
        int off = dd * 128 + ((a * 2) ^ ((dd & 7) << 4));
        cct[off >> 1] = f2bf(v);
    }
}

// ---------------- k_main ----------------
// 1024 threads (16 waves), 256-row grid tiles, 4 tiles per block.
// dynamic LDS layout (bytes):
//   0      : W2 bf16 swz [128][256B]
//   32768  : W3 bf16 swz [128][256B]
//   65536  : cct bf16 swz [128][128B]
//   81920  : bufA 64KB (gto [256][128B] -> v1/v2 [256][256B])
//   147456 : dens[256] f32
//   148480 : us ; 148992 wcs ; 149504 b2s ; 150016 b3s ; 150528 wps ;
//   151040 : zqs[128] f32  -> total 151552
#define SMEM_MAIN 151552

__global__ __launch_bounds__(1024, 4)
void k_main(const float* __restrict__ dmat, const float* __restrict__ wfunc_b,
            const float* __restrict__ wprop_w, float* __restrict__ out,
            char* __restrict__ ws)
{
    extern __shared__ char lds[];
    unsigned short* W2s = (unsigned short*)(lds);
    unsigned short* W3s = (unsigned short*)(lds + 32768);
    unsigned short* CTs = (unsigned short*)(lds + 65536);
    char* bufA = lds + 81920;
    float* dens = (float*)(lds + 147456);
    float* us   = (float*)(lds + 148480);
    float* wcs  = (float*)(lds + 148992);
    float* b2s  = (float*)(lds + 149504);
    float* b3s  = (float*)(lds + 150016);
    float* wps  = (float*)(lds + 150528);
    float* zqs  = (float*)(lds + 151040);

    const int t = threadIdx.x;
    const int b = blockIdx.x >> 5;
    const int blk = blockIdx.x & 31;

    {   // stage weights / constants
        const uint4* s2 = (const uint4*)(ws + WS_W2);
        const uint4* s3 = (const uint4*)(ws + WS_W3);
        const uint4* sc = (const uint4*)(ws + WS_CCT + (size_t)b * 16384u);
        uint4* d2 = (uint4*)W2s; uint4* d3 = (uint4*)W3s; uint4* dc = (uint4*)CTs;
        for (int i = t; i < 2048; i += 1024) { d2[i] = s2[i]; d3[i] = s3[i]; }
        if (t < 1024) dc[t] = sc[t];
        const float* uw = (const float*)(ws + WS_UW);
        if (t < 128) {
            us[t]  = uw[t];
            wcs[t] = uw[128 + t];
            b2s[t] = wfunc_b[128 + t];
            b3s[t] = wfunc_b[256 + t];
            wps[t] = wprop_w[t];
            zqs[t] = ((const float*)(ws + WS_ZQ))[b * 128 + t];
        }
    }

    const int wv = t >> 6, l = t & 63;
    const int gsel = wv >> 1, dsel = wv & 1;     // 8 g-bands x 2 d-halves
    const int lrow = l & 15, lk = l >> 4;
    const int srow = t >> 2, q4 = t & 3;         // staging: row, quarter

    const float* dbase = dmat + (size_t)b * GG * AA;
    float esum = 0.f;

    float4 pf[4];
    {
        const float4* p = (const float4*)(dbase + (size_t)(blk * 256 + srow) * AA + q4 * 16);
        #pragma unroll
        for (int k = 0; k < 4; ++k) pf[k] = p[k];
    }
    __syncthreads();

    for (int it = 0; it < 4; ++it) {
        // ---- phase 1: gto -> bufA (bf16, stride 128B, swizzled) ----
        #pragma unroll
        for (int c = 0; c < 2; ++c) {
            float v[8] = {pf[2*c].x, pf[2*c].y, pf[2*c].z, pf[2*c].w,
                          pf[2*c+1].x, pf[2*c+1].y, pf[2*c+1].z, pf[2*c+1].w};
            unsigned int wd[4];
            #pragma unroll
            for (int h = 0; h < 4; ++h) {
                unsigned short q2[2];
                #pragma unroll
                for (int jj = 0; jj < 2; ++jj) {
                    int j = 2 * h + jj;
                    int a = q4 * 16 + c * 8 + j;
                    float zzv = zqs[2 * a], qmv = zqs[2 * a + 1];
                    float dv = v[j];
                    float ttv = zzv * dv;
                    float ex = __expf(-ttv * ttv);
                    float pw = (qmv < 0.5f) ? 1.f : ((qmv < 1.5f) ? dv : dv * dv);
                    q2[jj] = f2bf(pw * ex);
                }
                wd[h] = (unsigned int)q2[0] | ((unsigned int)q2[1] << 16);
            }
            int colB = q4 * 32 + c * 16;
            int off = srow * 128 + (colB ^ ((srow & 7) << 4));
            *(uint4*)(bufA + off) = make_uint4(wd[0], wd[1], wd[2], wd[3]);
        }
        if (t < 256) dens[t] = 0.f;

        // ---- phase 2: prefetch next tile's distances ----
        if (it < 3) {
            int nt = blk + 32 * (it + 1);
            const float4* p = (const float4*)(dbase + (size_t)(nt * 256 + srow) * AA + q4 * 16);
            #pragma unroll
            for (int k = 0; k < 4; ++k) pf[k] = p[k];
        }
        __syncthreads();

        // ---- phase 3: mo GEMM (K=64) + density ----
        {
            f32x4 acc[2][4];
            #pragma unroll
            for (int i = 0; i < 2; ++i)
                #pragma unroll
                for (int j = 0; j < 4; ++j) acc[i][j] = (f32x4){0.f, 0.f, 0.f, 0.f};
            #pragma unroll
            for (int kt = 0; kt < 2; ++kt) {
                bf16x8 af[2], bfv[4];
                int colB = kt * 64 + lk * 16;
                #pragma unroll
                for (int i = 0; i < 2; ++i) {
                    int gr = (gsel * 2 + i) * 16 + lrow;
                    af[i] = *(const bf16x8*)(bufA + gr * 128 + (colB ^ ((gr & 7) << 4)));
                }
                #pragma unroll
                for (int j = 0; j < 4; ++j) {
                    int dr = (dsel * 4 + j) * 16 + lrow;
                    bfv[j] = *(const bf16x8*)((const char*)CTs + dr * 128 + (colB ^ ((dr & 7) << 4)));
                }
                #pragma unroll
                for (int i = 0; i < 2; ++i)
                    #pragma unroll
                    for (int j = 0; j < 4; ++j)
                        acc[i][j] = __builtin_amdgcn_mfma_f32_16x16x32_bf16(af[i], bfv[j], acc[i][j], 0, 0, 0);
            }
            #pragma unroll
            for (int i = 0; i < 2; ++i) {
                float ds4[4] = {0.f, 0.f, 0.f, 0.f};
                #pragma unroll
                for (int j = 0; j < 4; ++j)
                    #pragma unroll
                    for (int r = 0; r < 4; ++r) { float m = acc[i][j][r]; ds4[r] += m * m; }
                #pragma unroll
                for (int r = 0; r < 4; ++r) {
                    float vv = ds4[r];
                    vv += __shfl_xor(vv, 1); vv += __shfl_xor(vv, 2);
                    vv += __shfl_xor(vv, 4); vv += __shfl_xor(vv, 8);
                    if (lrow == 0) atomicAdd(&dens[(gsel * 2 + i) * 16 + lk * 4 + r], vv);
                }
            }
        }
        __syncthreads();

        // ---- phase 4: v1 = relu(dens*u + w) -> bufA (bf16, stride 256B) ----
        {
            float dv = dens[srow];
            #pragma unroll
            for (int c = 0; c < 4; ++c) {
                unsigned int wd[4];
                #pragma unroll
                for (int h = 0; h < 4; ++h) {
                    unsigned short q2[2];
                    #pragma unroll
                    for (int jj = 0; jj < 2; ++jj) {
                        int di = q4 * 32 + c * 8 + 2 * h + jj;
                        q2[jj] = f2bf(fmaxf(dv * us[di] + wcs[di], 0.f));
                    }
                    wd[h] = (unsigned int)q2[0] | ((unsigned int)q2[1] << 16);
                }
                int colB = q4 * 64 + c * 16;
                int off = srow * 256 + (colB ^ ((srow & 7) << 4));
                *(uint4*)(bufA + off) = make_uint4(wd[0], wd[1], wd[2], wd[3]);
            }
        }
        __syncthreads();

        // ---- phase 5: L2 GEMM ----
        f32x4 acc2[2][4];
        {
            #pragma unroll
            for (int i = 0; i < 2; ++i)
                #pragma unroll
                for (int j = 0; j < 4; ++j) acc2[i][j] = (f32x4){0.f, 0.f, 0.f, 0.f};
            #pragma unroll
            for (int kt = 0; kt < 4; ++kt) {
                bf16x8 af[2], bfv[4];
                int colB = kt * 64 + lk * 16;
                #pragma unroll
                for (int i = 0; i < 2; ++i) {
                    int gr = (gsel * 2 + i) * 16 + lrow;
                    af[i] = *(const bf16x8*)(bufA + gr * 256 + (colB ^ ((gr & 7) << 4)));
                }
                #pragma unroll
                for (int j = 0; j < 4; ++j) {
                    int er = (dsel * 4 + j) * 16 + lrow;
                    bfv[j] = *(const bf16x8*)((const char*)W2s + er * 256 + (colB ^ ((er & 7) << 4)));
                }
                #pragma unroll
                for (int i = 0; i < 2; ++i)
                    #pragma unroll
                    for (int j = 0; j < 4; ++j)
                        acc2[i][j] = __builtin_amdgcn_mfma_f32_16x16x32_bf16(af[i], bfv[j], acc2[i][j], 0, 0, 0);
            }
        }
        __syncthreads();

        // ---- phase 6: v2 = relu(acc2 + b2) -> bufA ----
        #pragma unroll
        for (int j = 0; j < 4; ++j) {
            int e = (dsel * 4 + j) * 16 + lrow;
            float bias = b2s[e];
            #pragma unroll
            for (int i = 0; i < 2; ++i)
                #pragma unroll
                for (int r = 0; r < 4; ++r) {
                    int g = (gsel * 2 + i) * 16 + lk * 4 + r;
                    float vv = fmaxf(acc2[i][j][r] + bias, 0.f);
                    int off = g * 256 + ((e * 2) ^ ((g & 7) << 4));
                    *(unsigned short*)(bufA + off) = f2bf(vv);
                }
        }
        __syncthreads();

        // ---- phase 7: L3 GEMM ----
        f32x4 acc3[2][4];
        {
            #pragma unroll
            for (int i = 0; i < 2; ++i)
                #pragma unroll
                for (int j = 0; j < 4; ++j) acc3[i][j] = (f32x4){0.f, 0.f, 0.f, 0.f};
            #pragma unroll
            for (int kt = 0; kt < 4; ++kt) {
                bf16x8 af[2], bfv[4];
                int colB = kt * 64 + lk * 16;
                #pragma unroll
                for (int i = 0; i < 2; ++i) {
                    int gr = (gsel * 2 + i) * 16 + lrow;
                    af[i] = *(const bf16x8*)(bufA + gr * 256 + (colB ^ ((gr & 7) << 4)));
                }
                #pragma unroll
                for (int j = 0; j < 4; ++j) {
                    int er = (dsel * 4 + j) * 16 + lrow;
                    bfv[j] = *(const bf16x8*)((const char*)W3s + er * 256 + (colB ^ ((er & 7) << 4)));
                }
                #pragma unroll
                for (int i = 0; i < 2; ++i)
                    #pragma unroll
                    for (int j = 0; j < 4; ++j)
                        acc3[i][j] = __builtin_amdgcn_mfma_f32_16x16x32_bf16(af[i], bfv[j], acc3[i][j], 0, 0, 0);
            }
        }

        // ---- phase 8: v3 = relu(acc3 + b3); esum += v3 . wprop ----
        #pragma unroll
        for (int j = 0; j < 4; ++j) {
            int e = (dsel * 4 + j) * 16 + lrow;
            float bias = b3s[e], wpv = wps[e];
            #pragma unroll
            for (int i = 0; i < 2; ++i)
                #pragma unroll
                for (int r = 0; r < 4; ++r)
                    esum += fmaxf(acc3[i][j][r] + bias, 0.f) * wpv;
        }
        __syncthreads();   // protect bufA before next iteration's gto write
    }

    #pragma unroll
    for (int m = 1; m < 64; m <<= 1) esum += __shfl_xor(esum, m);
    if (l == 0) atomicAdd(&out[b], esum);
}

// ---------------- launcher ----------------
extern "C" void kernel_launch(void* const* d_in, const int* in_sizes, int n_in,
                              void* d_out, int out_size, void* d_ws, size_t ws_size,
                              hipStream_t stream)
{
    const float* dmat    = (const float*)d_in[0];
    const int*   q       = (const int*)d_in[1];
    const int*   ao      = (const int*)d_in[2];
    const float* Ne      = (const float*)d_in[3];
    const float* coef    = (const float*)d_in[4];
    const float* zeta    = (const float*)d_in[5];
    const float* wpre_w  = (const float*)d_in[6];
    const float* wpre_b  = (const float*)d_in[7];
    const float* wfunc_w = (const float*)d_in[8];
    const float* wfunc_b = (const float*)d_in[9];
    const float* wprop_w = (const float*)d_in[10];
    const float* wprop_b = (const float*)d_in[11];
    float* out = (float*)d_out;
    char*  ws  = (char*)d_ws;

    k_prep<<<263, 256, 0, stream>>>(q, ao, coef, zeta, wpre_w, wpre_b,
                                    wfunc_w, wfunc_b, wprop_b, out, ws);
    k_corr<<<1, 128, 0, stream>>>(wfunc_w, wfunc_b, wprop_w, out, ws);
    k_M<<<dim3(32, 8), 1024, 0, stream>>>(dmat, ws);
    k_cct<<<8, 256, 0, stream>>>(Ne, ws);
    hipFuncSetAttribute((const void*)k_main,
                        hipFuncAttributeMaxDynamicSharedMemorySize, SMEM_MAIN);
    k_main<<<256, 1024, SMEM_MAIN, stream>>>(dmat, wfunc_b, wprop_w, out, ws);
}

// Round 3
// 278.306 us; speedup vs baseline: 1.0363x; 1.0363x over previous
//
#include <hip/hip_runtime.h>
#include <stdint.h>

// QuantumDeepField — MI355X (gfx950)
// Pipeline:
//   k_prep   : c_n, z/q unpack, layer-1 fold, W2/W3 -> bf16 LINEAR ws,
//              out[b] = W_prop_b, zero M
//   k_corr   : systematic bf16-error correction at dens=0, adds G*corr to out
//   k_M      : M[b] = gto^T gto via MFMA (512 blocks x 512 thr)
//   k_cct    : S_mo = e^T M e ; cct[b][d][a] bf16 LINEAR
//   k_main   : 2048 blocks x 512 thr, one 128-row tile each:
//              gto -> mo (MFMA, B-frags from L2) -> density -> v1 ->
//              L2 GEMM -> L3 GEMM -> sum -> out[b]. LDS 33KB -> 2 blocks/CU.

#define BB 8
#define GG 32768
#define AA 64
#define DD 128
#define EPSF 1e-12f

// ---- workspace layout (byte offsets) ----
#define WS_M    0u          // [B][64][64] f32 Gram (131072 B)
#define WS_ZQ   131072u     // [B][64][2] f32 {zeta, q-1} (4096 B)
#define WS_CN   135168u     // [B][64][128] f32 c_n (262144 B)
#define WS_UW   397312u     // u[128], w[128] f32 (1024 B)
#define WS_CCT  398336u     // [B][128 d][64 a] bf16 linear (131072 B)
#define WS_W2   529408u     // [128 e][128 d] bf16 linear (32768 B)
#define WS_W3   562176u     // [128 e][128 d] bf16 linear (32768 B)

typedef __attribute__((ext_vector_type(8))) short bf16x8;
typedef __attribute__((ext_vector_type(4))) float f32x4;

__device__ __forceinline__ unsigned short f2bf(float f) {
    union { float f; unsigned int u; } x; x.f = f;
    unsigned int u = x.u + 0x7FFFu + ((x.u >> 16) & 1u);
    return (unsigned short)(u >> 16);
}
__device__ __forceinline__ float bfround(float f) {
    union { float f; unsigned int u; } x; x.f = f;
    unsigned int u = x.u + 0x7FFFu + ((x.u >> 16) & 1u);
    x.u = u & 0xFFFF0000u;
    return x.f;
}

// ---------------- k_prep ----------------
__global__ __launch_bounds__(256)
void k_prep(const int* __restrict__ q, const int* __restrict__ ao,
            const float* __restrict__ coef, const float* __restrict__ zeta,
            const float* __restrict__ wpre_w, const float* __restrict__ wpre_b,
            const float* __restrict__ wfunc_w, const float* __restrict__ wfunc_b,
            const float* __restrict__ wprop_b, float* __restrict__ out,
            char* __restrict__ ws)
{
    int tid = blockIdx.x * 256 + threadIdx.x;
    if (tid < 32768) {
        // W2/W3 -> bf16 linear [e][d]
        int lsel = tid >> 14;           // 0 -> layer 2, 1 -> layer 3
        int idx = tid & 16383;
        unsigned short* dst = (unsigned short*)(ws + (lsel == 0 ? WS_W2 : WS_W3));
        dst[idx] = f2bf(wfunc_w[(lsel + 1) * 16384 + idx]);
    } else if (tid < 33792) {
        // c_n: per-(b,d) L2 norm over A
        int i = tid - 32768;
        int b = i >> 7, dd = i & 127;
        float s = 0.f;
        for (int a = 0; a < AA; ++a) {
            float v = coef[ao[b * AA + a] * DD + dd];
            s += v * v;
        }
        float inv = 1.f / fmaxf(sqrtf(s), EPSF);
        float* cn = (float*)(ws + WS_CN);
        for (int a = 0; a < AA; ++a)
            cn[((size_t)b * AA + a) * DD + dd] = coef[ao[b * AA + a] * DD + dd] * inv;
    } else if (tid < 34304) {
        int i = tid - 33792;
        int b = i >> 6, a = i & 63;
        float* zq = (float*)(ws + WS_ZQ);
        zq[(b * AA + a) * 2 + 0] = zeta[ao[b * AA + a]];
        zq[(b * AA + a) * 2 + 1] = (float)q[b * AA + a];   // q-1 in {0,1,2}
    } else if (tid < 34432) {
        // fold layer-1: u = W1 @ w_pre ; w = W1 @ b_pre + b1
        int e = tid - 34304;
        float su = 0.f, sw = 0.f;
        for (int dd = 0; dd < DD; ++dd) {
            float wv = wfunc_w[e * DD + dd];
            su += wv * wpre_w[dd];
            sw += wv * wpre_b[dd];
        }
        float* uw = (float*)(ws + WS_UW);
        uw[e] = su;
        uw[128 + e] = sw + wfunc_b[e];
    } else if (tid < 34440) {
        out[tid - 34432] = wprop_b[0];
    } else if (tid < 67208) {
        ((float*)(ws + WS_M))[tid - 34440] = 0.f;
    }
}

// ---------------- k_corr : cancel systematic bf16 error ----------------
__global__ __launch_bounds__(128)
void k_corr(const float* __restrict__ wfunc_w, const float* __restrict__ wfunc_b,
            const float* __restrict__ wprop_w, float* __restrict__ out,
            char* __restrict__ ws)
{
    __shared__ float v1e[128], v1b[128], v2e[128], v2b[128];
    __shared__ float part[2];
    int t = threadIdx.x;
    const float* uw = (const float*)(ws + WS_UW);
    float w0 = uw[128 + t];
    float r = fmaxf(w0, 0.f);
    v1e[t] = r;
    v1b[t] = bfround(r);
    __syncthreads();
    float ze = wfunc_b[128 + t], zb = ze;
    for (int dd = 0; dd < 128; ++dd) {
        float wv = wfunc_w[16384 + t * 128 + dd];
        ze += wv * v1e[dd];
        zb += bfround(wv) * v1b[dd];
    }
    v2e[t] = fmaxf(ze, 0.f);
    v2b[t] = bfround(fmaxf(zb, 0.f));
    __syncthreads();
    float ye = wfunc_b[256 + t], yb = ye;
    for (int dd = 0; dd < 128; ++dd) {
        float wv = wfunc_w[32768 + t * 128 + dd];
        ye += wv * v2e[dd];
        yb += bfround(wv) * v2b[dd];
    }
    float wpv = wprop_w[t];
    float diff = (fmaxf(ye, 0.f) - fmaxf(yb, 0.f)) * wpv;
    #pragma unroll
    for (int m = 1; m < 64; m <<= 1) diff += __shfl_xor(diff, m);
    if ((t & 63) == 0) part[t >> 6] = diff;
    __syncthreads();
    if (t == 0) {
        float corr = (part[0] + part[1]) * (float)GG;
        #pragma unroll
        for (int b = 0; b < BB; ++b) atomicAdd(&out[b], corr);
    }
}

// ---------------- k_M : Gram matrix via MFMA ----------------
// grid (64, B), 512 threads. Each block: 512 g's = 4 tiles of 128.
// LDS: gto transposed [64 a][128 g] bf16, 256B rows, XOR-swizzled.
__global__ __launch_bounds__(512, 4)
void k_M(const float* __restrict__ dmat, char* __restrict__ ws)
{
    __shared__ unsigned short gs[8192];   // 16 KB
    const int b = blockIdx.y;
    const int chunk = blockIdx.x;         // 0..63
    const int t = threadIdx.x;
    const int g4 = t & 31;                // 4-g group within tile
    const int a4 = t >> 5;                // 4-a group (0..15)

    const float* zqp = (const float*)(ws + WS_ZQ) + b * 128;
    float4 zq0 = *(const float4*)(zqp + a4 * 8);
    float4 zq1 = *(const float4*)(zqp + a4 * 8 + 4);
    float zz[4] = {zq0.x, zq0.z, zq1.x, zq1.z};
    float qm[4] = {zq0.y, zq0.w, zq1.y, zq1.w};

    const int wv = t >> 6, l = t & 63;
    const int ta = wv >> 1, tb0 = (wv & 1) * 2;
    const int lrow = l & 15, lk = l >> 4;

    const float* dbase = dmat + (size_t)b * GG * AA + (size_t)chunk * 512 * AA;

    f32x4 acc[2];
    acc[0] = (f32x4){0.f, 0.f, 0.f, 0.f};
    acc[1] = (f32x4){0.f, 0.f, 0.f, 0.f};

    float4 pf[4];
    #pragma unroll
    for (int gg = 0; gg < 4; ++gg)
        pf[gg] = *(const float4*)(dbase + (size_t)(g4 * 4 + gg) * AA + a4 * 4);

    for (int tt = 0; tt < 4; ++tt) {
        float gv[4][4];
        #pragma unroll
        for (int gg = 0; gg < 4; ++gg) {
            float dvv[4] = {pf[gg].x, pf[gg].y, pf[gg].z, pf[gg].w};
            #pragma unroll
            for (int j = 0; j < 4; ++j) {
                float ttv = zz[j] * dvv[j];
                float ex = __expf(-ttv * ttv);
                float pw = (qm[j] < 0.5f) ? 1.f : ((qm[j] < 1.5f) ? dvv[j] : dvv[j] * dvv[j]);
                gv[gg][j] = pw * ex;
            }
        }
        if (tt < 3) {
            #pragma unroll
            for (int gg = 0; gg < 4; ++gg)
                pf[gg] = *(const float4*)(dbase + (size_t)((tt + 1) * 128 + g4 * 4 + gg) * AA + a4 * 4);
        }
        // store transposed: row a, 4 consecutive g packed (b64)
        #pragma unroll
        for (int j = 0; j < 4; ++j) {
            int a = a4 * 4 + j;
            unsigned int lo = (unsigned int)f2bf(gv[0][j]) | ((unsigned int)f2bf(gv[1][j]) << 16);
            unsigned int hi = (unsigned int)f2bf(gv[2][j]) | ((unsigned int)f2bf(gv[3][j]) << 16);
            int off = a * 256 + ((g4 * 8) ^ ((a & 7) << 4));
            *(uint2*)((char*)gs + off) = make_uint2(lo, hi);
        }
        __syncthreads();
        #pragma unroll
        for (int kt = 0; kt < 4; ++kt) {
            int colB = kt * 64 + lk * 16;
            int ra = ta * 16 + lrow;
            bf16x8 af = *(const bf16x8*)((const char*)gs + ra * 256 + (colB ^ ((ra & 7) << 4)));
            #pragma unroll
            for (int jj = 0; jj < 2; ++jj) {
                int rb = (tb0 + jj) * 16 + lrow;
                bf16x8 bv = *(const bf16x8*)((const char*)gs + rb * 256 + (colB ^ ((rb & 7) << 4)));
                acc[jj] = __builtin_amdgcn_mfma_f32_16x16x32_bf16(af, bv, acc[jj], 0, 0, 0);
            }
        }
        __syncthreads();
    }
    float* Mg = (float*)(ws + WS_M) + b * 4096;
    #pragma unroll
    for (int jj = 0; jj < 2; ++jj)
        #pragma unroll
        for (int r = 0; r < 4; ++r)
            atomicAdd(&Mg[(ta * 16 + lk * 4 + r) * 64 + (tb0 + jj) * 16 + lrow], acc[jj][r]);
}

// ---------------- k_cct : S_mo = e^T M e ; folded coeffs (linear) ----------------
__global__ __launch_bounds__(256)
void k_cct(const float* __restrict__ Ne, char* __restrict__ ws)
{
    __shared__ float M[64][64];
    __shared__ float e_s[128][65];
    __shared__ float inv_na[64];
    __shared__ float alpha[128];
    const int b = blockIdx.x, t = threadIdx.x;
    const float* Mg = (const float*)(ws + WS_M) + b * 4096;
    for (int i = t; i < 4096; i += 256) ((float*)M)[i] = Mg[i];
    __syncthreads();
    if (t < 64) inv_na[t] = 1.f / fmaxf(sqrtf(M[t][t]), EPSF);
    __syncthreads();
    const float* cn = (const float*)(ws + WS_CN) + (size_t)b * AA * DD;
    for (int i = t; i < 8192; i += 256) {
        int a = i >> 7, dd = i & 127;
        e_s[dd][a] = cn[a * DD + dd] * inv_na[a];
    }
    __syncthreads();
    const int d = t >> 1, half = t & 1;
    float y[32];
    #pragma unroll
    for (int j = 0; j < 32; ++j) y[j] = 0.f;
    for (int a = 0; a < 64; ++a) {
        float ea = e_s[d][a];
        const float4* Mr = (const float4*)&M[a][half * 32];
        #pragma unroll 8
        for (int j4 = 0; j4 < 8; ++j4) {
            float4 mv = Mr[j4];
            y[4 * j4 + 0] += ea * mv.x; y[4 * j4 + 1] += ea * mv.y;
            y[4 * j4 + 2] += ea * mv.z; y[4 * j4 + 3] += ea * mv.w;
        }
    }
    float s = 0.f;
    #pragma unroll 8
    for (int j = 0; j < 32; ++j) s += e_s[d][half * 32 + j] * y[j];
    s += __shfl_xor(s, 1);
    if (half == 0) alpha[d] = sqrtf(Ne[b] * (1.f / 128.f)) / fmaxf(sqrtf(s), EPSF);
    __syncthreads();
    unsigned short* cct = (unsigned short*)(ws + WS_CCT) + (size_t)b * 8192;
    for (int i = t; i < 8192; i += 256) {
        int dd = i >> 6, a = i & 63;
        cct[i] = f2bf(e_s[dd][a] * alpha[dd]);   // linear [d][a]
    }
}

// ---------------- k_main ----------------
// 2048 blocks x 512 threads, one 128-row grid tile per block.
// LDS: bufA 32KB (gto [128][128B] -> v1/v2 [128][256B], XOR-swz) + dens + bsum.
__global__ __launch_bounds__(512, 4)
void k_main(const float* __restrict__ dmat, const float* __restrict__ wfunc_b,
            const float* __restrict__ wprop_w, float* __restrict__ out,
            char* __restrict__ ws)
{
    __shared__ char bufA[32768];
    __shared__ float dens[128];
    __shared__ float bsum;

    const int t = threadIdx.x;
    const int b = blockIdx.x >> 8;
    const int tile = blockIdx.x & 255;

    const int wv = t >> 6, l = t & 63;
    const int gsel = wv >> 1, dsel = wv & 1;   // 4 g-bands x 2 d-halves
    const int lrow = l & 15, lk = l >> 4;
    const int srow = t >> 2, q4 = t & 3;       // staging: row, quarter

    const char* Wcct = (const char*)(ws + WS_CCT) + (size_t)b * 16384u;
    const char* W2g  = (const char*)(ws + WS_W2);
    const char* W3g  = (const char*)(ws + WS_W3);
    const float* zqp = (const float*)(ws + WS_ZQ) + b * 128;
    const float* uwp = (const float*)(ws + WS_UW);

    if (t < 128) dens[t] = 0.f;
    if (t == 0) bsum = 0.f;

    // ---- phase 1: gto -> bufA (bf16, 128B rows, swizzled) ----
    {
        const float* drow = dmat + ((size_t)b * GG + (size_t)tile * 128 + srow) * AA + q4 * 16;
        #pragma unroll
        for (int c = 0; c < 2; ++c) {
            float4 d0 = *(const float4*)(drow + c * 8);
            float4 d1 = *(const float4*)(drow + c * 8 + 4);
            const float* zb = zqp + (q4 * 16 + c * 8) * 2;
            float dvv[8] = {d0.x, d0.y, d0.z, d0.w, d1.x, d1.y, d1.z, d1.w};
            unsigned int wd[4];
            #pragma unroll
            for (int h = 0; h < 4; ++h) {
                unsigned short q2[2];
                #pragma unroll
                for (int jj = 0; jj < 2; ++jj) {
                    int j = h * 2 + jj;
                    float zzv = zb[j * 2], qmv = zb[j * 2 + 1];
                    float dv = dvv[j];
                    float ttv = zzv * dv;
                    float ex = __expf(-ttv * ttv);
                    float pw = (qmv < 0.5f) ? 1.f : ((qmv < 1.5f) ? dv : dv * dv);
                    q2[jj] = f2bf(pw * ex);
                }
                wd[h] = (unsigned int)q2[0] | ((unsigned int)q2[1] << 16);
            }
            int colB = q4 * 32 + c * 16;
            *(uint4*)(bufA + srow * 128 + (colB ^ ((srow & 7) << 4))) =
                make_uint4(wd[0], wd[1], wd[2], wd[3]);
        }
    }
    __syncthreads();

    // ---- phase 2: mo GEMM (K=64, B-frags from L2) + density ----
    {
        f32x4 acc[2][4];
        #pragma unroll
        for (int i = 0; i < 2; ++i)
            #pragma unroll
            for (int j = 0; j < 4; ++j) acc[i][j] = (f32x4){0.f, 0.f, 0.f, 0.f};
        #pragma unroll
        for (int kt = 0; kt < 2; ++kt) {
            int colB = kt * 64 + lk * 16;
            bf16x8 af[2], bv[4];
            #pragma unroll
            for (int i = 0; i < 2; ++i) {
                int gr = (gsel * 2 + i) * 16 + lrow;
                af[i] = *(const bf16x8*)(bufA + gr * 128 + (colB ^ ((gr & 7) << 4)));
            }
            #pragma unroll
            for (int j = 0; j < 4; ++j) {
                int dr = (dsel * 4 + j) * 16 + lrow;
                bv[j] = *(const bf16x8*)(Wcct + dr * 128 + colB);
            }
            #pragma unroll
            for (int i = 0; i < 2; ++i)
                #pragma unroll
                for (int j = 0; j < 4; ++j)
                    acc[i][j] = __builtin_amdgcn_mfma_f32_16x16x32_bf16(af[i], bv[j], acc[i][j], 0, 0, 0);
        }
        #pragma unroll
        for (int i = 0; i < 2; ++i) {
            float ds4[4] = {0.f, 0.f, 0.f, 0.f};
            #pragma unroll
            for (int j = 0; j < 4; ++j)
                #pragma unroll
                for (int r = 0; r < 4; ++r) { float m = acc[i][j][r]; ds4[r] += m * m; }
            #pragma unroll
            for (int r = 0; r < 4; ++r) {
                float vv = ds4[r];
                vv += __shfl_xor(vv, 1); vv += __shfl_xor(vv, 2);
                vv += __shfl_xor(vv, 4); vv += __shfl_xor(vv, 8);
                if (lrow == 0) atomicAdd(&dens[(gsel * 2 + i) * 16 + lk * 4 + r], vv);
            }
        }
    }
    __syncthreads();

    // ---- phase 3: v1 = relu(dens*u + w) -> bufA (bf16, 256B rows) ----
    {
        float dv = dens[srow];
        #pragma unroll
        for (int c = 0; c < 4; ++c) {
            int di0 = q4 * 32 + c * 8;
            float4 ua = *(const float4*)(uwp + di0);
            float4 ub = *(const float4*)(uwp + di0 + 4);
            float4 wa = *(const float4*)(uwp + 128 + di0);
            float4 wb = *(const float4*)(uwp + 128 + di0 + 4);
            float uu[8] = {ua.x, ua.y, ua.z, ua.w, ub.x, ub.y, ub.z, ub.w};
            float wwv[8] = {wa.x, wa.y, wa.z, wa.w, wb.x, wb.y, wb.z, wb.w};
            unsigned int wd[4];
            #pragma unroll
            for (int h = 0; h < 4; ++h) {
                unsigned short q2[2];
                #pragma unroll
                for (int jj = 0; jj < 2; ++jj)
                    q2[jj] = f2bf(fmaxf(dv * uu[h * 2 + jj] + wwv[h * 2 + jj], 0.f));
                wd[h] = (unsigned int)q2[0] | ((unsigned int)q2[1] << 16);
            }
            int colB = q4 * 64 + c * 16;
            *(uint4*)(bufA + srow * 256 + (colB ^ ((srow & 7) << 4))) =
                make_uint4(wd[0], wd[1], wd[2], wd[3]);
        }
    }
    __syncthreads();

    // ---- phase 4: L2 GEMM (W2 frags from L2) ----
    f32x4 acc2[2][4];
    {
        #pragma unroll
        for (int i = 0; i < 2; ++i)
            #pragma unroll
            for (int j = 0; j < 4; ++j) acc2[i][j] = (f32x4){0.f, 0.f, 0.f, 0.f};
        #pragma unroll
        for (int kt = 0; kt < 4; ++kt) {
            int colB = kt * 64 + lk * 16;
            bf16x8 af[2], bv[4];
            #pragma unroll
            for (int i = 0; i < 2; ++i) {
                int gr = (gsel * 2 + i) * 16 + lrow;
                af[i] = *(const bf16x8*)(bufA + gr * 256 + (colB ^ ((gr & 7) << 4)));
            }
            #pragma unroll
            for (int j = 0; j < 4; ++j) {
                int er = (dsel * 4 + j) * 16 + lrow;
                bv[j] = *(const bf16x8*)(W2g + er * 256 + colB);
            }
            #pragma unroll
            for (int i = 0; i < 2; ++i)
                #pragma unroll
                for (int j = 0; j < 4; ++j)
                    acc2[i][j] = __builtin_amdgcn_mfma_f32_16x16x32_bf16(af[i], bv[j], acc2[i][j], 0, 0, 0);
        }
    }
    __syncthreads();

    // ---- phase 5: v2 = relu(acc2 + b2) -> bufA ----
    #pragma unroll
    for (int j = 0; j < 4; ++j) {
        int e = (dsel * 4 + j) * 16 + lrow;
        float bias = wfunc_b[128 + e];
        #pragma unroll
        for (int i = 0; i < 2; ++i)
            #pragma unroll
            for (int r = 0; r < 4; ++r) {
                int g = (gsel * 2 + i) * 16 + lk * 4 + r;
                float vv = fmaxf(acc2[i][j][r] + bias, 0.f);
                *(unsigned short*)(bufA + g * 256 + ((e * 2) ^ ((g & 7) << 4))) = f2bf(vv);
            }
    }
    __syncthreads();

    // ---- phase 6: L3 GEMM (W3 frags from L2) ----
    f32x4 acc3[2][4];
    {
        #pragma unroll
        for (int i = 0; i < 2; ++i)
            #pragma unroll
            for (int j = 0; j < 4; ++j) acc3[i][j] = (f32x4){0.f, 0.f, 0.f, 0.f};
        #pragma unroll
        for (int kt = 0; kt < 4; ++kt) {
            int colB = kt * 64 + lk * 16;
            bf16x8 af[2], bv[4];
            #pragma unroll
            for (int i = 0; i < 2; ++i) {
                int gr = (gsel * 2 + i) * 16 + lrow;
                af[i] = *(const bf16x8*)(bufA + gr * 256 + (colB ^ ((gr & 7) << 4)));
            }
            #pragma unroll
            for (int j = 0; j < 4; ++j) {
                int er = (dsel * 4 + j) * 16 + lrow;
                bv[j] = *(const bf16x8*)(W3g + er * 256 + colB);
            }
            #pragma unroll
            for (int i = 0; i < 2; ++i)
                #pragma unroll
                for (int j = 0; j < 4; ++j)
                    acc3[i][j] = __builtin_amdgcn_mfma_f32_16x16x32_bf16(af[i], bv[j], acc3[i][j], 0, 0, 0);
        }
    }

    // ---- phase 7: v3 = relu(acc3 + b3); esum += v3 . wprop ----
    float esum = 0.f;
    #pragma unroll
    for (int j = 0; j < 4; ++j) {
        int e = (dsel * 4 + j) * 16 + lrow;
        float bias = wfunc_b[256 + e], wpv = wprop_w[e];
        #pragma unroll
        for (int i = 0; i < 2; ++i)
            #pragma unroll
            for (int r = 0; r < 4; ++r)
                esum += fmaxf(acc3[i][j][r] + bias, 0.f) * wpv;
    }
    #pragma unroll
    for (int m = 1; m < 64; m <<= 1) esum += __shfl_xor(esum, m);
    if (l == 0) atomicAdd(&bsum, esum);
    __syncthreads();
    if (t == 0) atomicAdd(&out[b], bsum);
}

// ---------------- launcher ----------------
extern "C" void kernel_launch(void* const* d_in, const int* in_sizes, int n_in,
                              void* d_out, int out_size, void* d_ws, size_t ws_size,
                              hipStream_t stream)
{
    const float* dmat    = (const float*)d_in[0];
    const int*   q       = (const int*)d_in[1];
    const int*   ao      = (const int*)d_in[2];
    const float* Ne      = (const float*)d_in[3];
    const float* coef    = (const float*)d_in[4];
    const float* zeta    = (const float*)d_in[5];
    const float* wpre_w  = (const float*)d_in[6];
    const float* wpre_b  = (const float*)d_in[7];
    const float* wfunc_w = (const float*)d_in[8];
    const float* wfunc_b = (const float*)d_in[9];
    const float* wprop_w = (const float*)d_in[10];
    const float* wprop_b = (const float*)d_in[11];
    float* out = (float*)d_out;
    char*  ws  = (char*)d_ws;

    k_prep<<<263, 256, 0, stream>>>(q, ao, coef, zeta, wpre_w, wpre_b,
                                    wfunc_w, wfunc_b, wprop_b, out, ws);
    k_corr<<<1, 128, 0, stream>>>(wfunc_w, wfunc_b, wprop_w, out, ws);
    k_M<<<dim3(64, 8), 512, 0, stream>>>(dmat, ws);
    k_cct<<<8, 256, 0, stream>>>(Ne, ws);
    k_main<<<2048, 512, 0, stream>>>(dmat, wfunc_b, wprop_w, out, ws);
}